// Round 2
// baseline (86.333 us; speedup 1.0000x reference)
//
#include <hip/hip_runtime.h>
#include <hip/hip_bf16.h>
#include <stdint.h>

#define BB 32
#define NN 1024
#define MM 1024
#define DD 256

#define BM 128
#define BN 128
#define BK 64
#define KSTEPS (DD / BK)   // 4

typedef __attribute__((ext_vector_type(8))) short short8;
typedef __attribute__((ext_vector_type(4))) float floatx4;

__device__ inline unsigned short f2bf(float x) {
    union { __hip_bfloat16 h; unsigned short u; } cv;
    cv.h = __float2bfloat16(x);
    return cv.u;
}

// async global->LDS, 16B per lane. LDS dest = wave-uniform base + lane*16.
__device__ inline void async_copy16(void* lds, const void* g) {
    __builtin_amdgcn_global_load_lds(
        (const __attribute__((address_space(1))) unsigned int*)g,
        (__attribute__((address_space(3))) unsigned int*)lds, 16, 0, 0);
}

// ---------------------------------------------------------------------------
__global__ __launch_bounds__(256) void init_minbuf(unsigned int* __restrict__ p) {
    p[blockIdx.x * 256 + threadIdx.x] = 0x7F800000u; // +inf
}

// ---------------------------------------------------------------------------
// Convert fp32 -> bf16 + per-row sum of squares (fp32 exact). One wave/row.
// ---------------------------------------------------------------------------
__global__ __launch_bounds__(256) void convert_kernel(
        const float* __restrict__ h1, const float* __restrict__ h2,
        __hip_bfloat16* __restrict__ h1b, __hip_bfloat16* __restrict__ h2b,
        float* __restrict__ sq1, float* __restrict__ sq2) {
    int wave = blockIdx.x * 4 + (threadIdx.x >> 6);
    int lane = threadIdx.x & 63;
    const int total1 = BB * NN;

    const float* src;
    __hip_bfloat16* dst;
    float* sq;
    int row;
    if (wave < total1) { src = h1; dst = h1b; sq = sq1; row = wave; }
    else               { src = h2; dst = h2b; sq = sq2; row = wave - total1; }

    const float4* p = (const float4*)(src + (size_t)row * DD);
    float4 v = p[lane];

    float s = v.x * v.x + v.y * v.y + v.z * v.z + v.w * v.w;
    #pragma unroll
    for (int off = 32; off; off >>= 1) s += __shfl_xor(s, off, 64);

    ushort4 o;
    o.x = f2bf(v.x); o.y = f2bf(v.y); o.z = f2bf(v.z); o.w = f2bf(v.w);
    *(ushort4*)((unsigned short*)(dst + (size_t)row * DD) + lane * 4) = o;

    if (lane == 0) sq[row] = s;
}

// ---------------------------------------------------------------------------
// Batched GEMM + fused Hausdorff epilogue.
// 128x128 tile, BK=64, double-buffered global_load_lds staging with
// XOR-swizzled LDS layout (swizzle on global src + on ds_read; linear dest).
// ---------------------------------------------------------------------------
__global__ __launch_bounds__(256) void gemm_kernel(
        const __hip_bfloat16* __restrict__ h1b, const __hip_bfloat16* __restrict__ h2b,
        const float* __restrict__ sq1, const float* __restrict__ sq2,
        unsigned int* __restrict__ rowmin, unsigned int* __restrict__ colmin) {
    __shared__ __align__(16) unsigned short As[2][BM * BK];
    __shared__ __align__(16) unsigned short Bs[2][BN * BK];

    const int b    = blockIdx.y;
    const int tile = blockIdx.x;       // 0..63
    const int n0   = (tile >> 3) * BM;
    const int m0   = (tile & 7) * BN;

    const int tid  = threadIdx.x;
    const int wave = tid >> 6;
    const int lane = tid & 63;
    const int wn   = (wave >> 1) * 64;
    const int wm   = (wave & 1) * 64;

    const char* Ag = (const char*)(h1b + ((size_t)b * NN + n0) * DD);
    const char* Bg = (const char*)(h2b + ((size_t)b * MM + m0) * DD);

    // staging geometry: tile k-slice = 128 rows x 128 bytes = 16 chunks of 1KB.
    // wave handles 4 A-chunks + 4 B-chunks. Within a chunk, lane writes LDS
    // linearly at lane*16; global src col is inverse-XOR-swizzled.
    const int r_in   = lane >> 3;                       // 0..7 row within chunk
    const int srccol = (((lane & 7) ^ r_in) << 4);      // swizzled src byte col

    floatx4 acc[4][4] = {};

    const int krow = lane >> 4;   // 0..3
    const int rrow = lane & 15;   // 0..15
    const int rx   = rrow & 7;
    const int swzA = (wn + rrow) * 128;
    const int swzB = (wm + rrow) * 128;

    // prologue: stage ks=0 into buf 0
    {
        #pragma unroll
        for (int c = 0; c < 4; ++c) {
            int ch = wave * 4 + c;
            size_t goff = (size_t)(ch * 8 + r_in) * (DD * 2) + srccol;
            async_copy16((char*)&As[0][0] + ch * 1024, Ag + goff);
            async_copy16((char*)&Bs[0][0] + ch * 1024, Bg + goff);
        }
    }

    #pragma unroll
    for (int ks = 0; ks < KSTEPS; ++ks) {
        const int buf = ks & 1;
        if (ks < KSTEPS - 1) {
            // stage next k-slice into the other buffer (stays in flight)
            #pragma unroll
            for (int c = 0; c < 4; ++c) {
                int ch = wave * 4 + c;
                size_t goff = (size_t)(ch * 8 + r_in) * (DD * 2)
                            + (size_t)(ks + 1) * (BK * 2) + srccol;
                async_copy16((char*)&As[buf ^ 1][0] + ch * 1024, Ag + goff);
                async_copy16((char*)&Bs[buf ^ 1][0] + ch * 1024, Bg + goff);
            }
            asm volatile("s_waitcnt vmcnt(8)" ::: "memory");  // cur staged; 8 newest in flight
        } else {
            asm volatile("s_waitcnt vmcnt(0)" ::: "memory");
        }
        __builtin_amdgcn_s_barrier();
        __builtin_amdgcn_sched_barrier(0);

        const char* Ab = (const char*)&As[buf][0];
        const char* Bb = (const char*)&Bs[buf][0];
        #pragma unroll
        for (int kk = 0; kk < 2; ++kk) {
            const int swc = (((kk << 2) | krow) ^ rx) << 4;  // swizzled k-col byte
            short8 af[4], bfv[4];
            #pragma unroll
            for (int i = 0; i < 4; ++i)
                af[i] = *(const short8*)(Ab + swzA + i * 2048 + swc);
            #pragma unroll
            for (int j = 0; j < 4; ++j)
                bfv[j] = *(const short8*)(Bb + swzB + j * 2048 + swc);
            #pragma unroll
            for (int i = 0; i < 4; ++i)
                #pragma unroll
                for (int j = 0; j < 4; ++j)
                    acc[i][j] = __builtin_amdgcn_mfma_f32_16x16x32_bf16(
                        af[i], bfv[j], acc[i][j], 0, 0, 0);
        }
        __builtin_amdgcn_sched_barrier(0);
        __builtin_amdgcn_s_barrier();
    }

    // ---- epilogue ----
    // D mapping (16x16x32 bf16): col = lane&15, row = (lane>>4)*4 + reg
    const float* s1 = sq1 + b * NN + n0 + wn;
    const float* s2 = sq2 + b * MM + m0 + wm;
    unsigned int* rm = rowmin + b * NN + n0;
    unsigned int* cm = colmin + b * MM + m0;

    const int lrow = (lane >> 4) * 4;
    const int lcol = lane & 15;

    float s2v[4];
    #pragma unroll
    for (int j = 0; j < 4; ++j) s2v[j] = s2[j * 16 + lcol];

    float cmin[4] = {3.0e38f, 3.0e38f, 3.0e38f, 3.0e38f};

    #pragma unroll
    for (int i = 0; i < 4; ++i) {
        #pragma unroll
        for (int r = 0; r < 4; ++r) {
            float s1v = s1[i * 16 + lrow + r];
            float pm = 3.0e38f;
            #pragma unroll
            for (int j = 0; j < 4; ++j) {
                float dist = s1v + s2v[j] - 2.0f * acc[i][j][r];
                dist = fmaxf(dist, 0.0f);
                pm = fminf(pm, dist);
                cmin[j] = fminf(cmin[j], dist);
            }
            #pragma unroll
            for (int off = 1; off < 16; off <<= 1)
                pm = fminf(pm, __shfl_xor(pm, off, 64));
            if (lcol == 0)
                atomicMin(&rm[wn + i * 16 + lrow + r], __float_as_uint(pm));
        }
    }

    #pragma unroll
    for (int j = 0; j < 4; ++j) {
        float c = cmin[j];
        c = fminf(c, __shfl_xor(c, 16, 64));
        c = fminf(c, __shfl_xor(c, 32, 64));
        if ((lane >> 4) == 0)
            atomicMin(&cm[wm + j * 16 + lcol], __float_as_uint(c));
    }
}

// ---------------------------------------------------------------------------
__global__ __launch_bounds__(256) void finalize_kernel(
        const unsigned int* __restrict__ rowmin,
        const unsigned int* __restrict__ colmin,
        float* __restrict__ out) {
    int b = blockIdx.x;
    int tid = threadIdx.x;
    float s = 0.0f;
    for (int i = tid; i < NN; i += 256) s += __uint_as_float(rowmin[b * NN + i]);
    for (int i = tid; i < MM; i += 256) s += __uint_as_float(colmin[b * MM + i]);
    #pragma unroll
    for (int off = 32; off; off >>= 1) s += __shfl_xor(s, off, 64);
    __shared__ float wsum[4];
    if ((tid & 63) == 0) wsum[tid >> 6] = s;
    __syncthreads();
    if (tid == 0) out[b] = (wsum[0] + wsum[1] + wsum[2] + wsum[3]) * (1.0f / 1024.0f);
}

// ---------------------------------------------------------------------------
extern "C" void kernel_launch(void* const* d_in, const int* in_sizes, int n_in,
                              void* d_out, int out_size, void* d_ws, size_t ws_size,
                              hipStream_t stream) {
    const float* h1 = (const float*)d_in[0];
    const float* h2 = (const float*)d_in[1];
    float* out = (float*)d_out;

    char* ws = (char*)d_ws;
    const size_t bf_bytes = (size_t)BB * NN * DD * sizeof(unsigned short); // 16 MB
    __hip_bfloat16* h1b = (__hip_bfloat16*)ws;
    __hip_bfloat16* h2b = (__hip_bfloat16*)(ws + bf_bytes);
    float* sq1 = (float*)(ws + 2 * bf_bytes);
    float* sq2 = sq1 + BB * NN;
    unsigned int* rowmin = (unsigned int*)(sq2 + BB * MM);
    unsigned int* colmin = rowmin + BB * NN;

    hipLaunchKernelGGL(init_minbuf, dim3(256), dim3(256), 0, stream, rowmin);

    hipLaunchKernelGGL(convert_kernel, dim3((BB * NN + BB * MM) / 4), dim3(256), 0, stream,
                       h1, h2, h1b, h2b, sq1, sq2);

    hipLaunchKernelGGL(gemm_kernel, dim3(64, BB), dim3(256), 0, stream,
                       h1b, h2b, sq1, sq2, rowmin, colmin);

    hipLaunchKernelGGL(finalize_kernel, dim3(BB), dim3(256), 0, stream,
                       rowmin, colmin, out);
}

// Round 3
// 66.498 us; speedup vs baseline: 1.2983x; 1.2983x over previous
//
#include <hip/hip_runtime.h>
#include <hip/hip_bf16.h>
#include <stdint.h>

#define BB 32
#define NN 1024
#define MM 1024
#define DD 256

typedef __attribute__((ext_vector_type(8))) short short8;
typedef __attribute__((ext_vector_type(4))) float floatx4;

__device__ inline unsigned short f2bf(float x) {
    union { __hip_bfloat16 h; unsigned short u; } cv;
    cv.h = __float2bfloat16(x);
    return cv.u;
}

// async global->LDS, 16B per lane. LDS dest = wave-uniform base + lane*16.
__device__ inline void async_copy16(void* lds, const void* g) {
    __builtin_amdgcn_global_load_lds(
        (const __attribute__((address_space(1))) unsigned int*)g,
        (__attribute__((address_space(3))) unsigned int*)lds, 16, 0, 0);
}

// ---------------------------------------------------------------------------
__global__ __launch_bounds__(256) void init_minbuf(unsigned int* __restrict__ p) {
    p[blockIdx.x * 256 + threadIdx.x] = 0x7F800000u; // +inf
}

// ---------------------------------------------------------------------------
// Convert fp32 -> bf16 + per-row sum of squares (fp32 exact). One wave/row.
// ---------------------------------------------------------------------------
__global__ __launch_bounds__(256) void convert_kernel(
        const float* __restrict__ h1, const float* __restrict__ h2,
        __hip_bfloat16* __restrict__ h1b, __hip_bfloat16* __restrict__ h2b,
        float* __restrict__ sq1, float* __restrict__ sq2) {
    int wave = blockIdx.x * 4 + (threadIdx.x >> 6);
    int lane = threadIdx.x & 63;
    const int total1 = BB * NN;

    const float* src;
    __hip_bfloat16* dst;
    float* sq;
    int row;
    if (wave < total1) { src = h1; dst = h1b; sq = sq1; row = wave; }
    else               { src = h2; dst = h2b; sq = sq2; row = wave - total1; }

    const float4* p = (const float4*)(src + (size_t)row * DD);
    float4 v = p[lane];

    float s = v.x * v.x + v.y * v.y + v.z * v.z + v.w * v.w;
    #pragma unroll
    for (int off = 32; off; off >>= 1) s += __shfl_xor(s, off, 64);

    ushort4 o;
    o.x = f2bf(v.x); o.y = f2bf(v.y); o.z = f2bf(v.z); o.w = f2bf(v.w);
    *(ushort4*)((unsigned short*)(dst + (size_t)row * DD) + lane * 4) = o;

    if (lane == 0) sq[row] = s;
}

// ---------------------------------------------------------------------------
// A-resident batched GEMM + fused Hausdorff epilogue.
// Grid (32 batches, 8 n-tiles) -> 256 blocks, 1/CU (116 KB LDS).
// Each block: A panel 128x256 staged once -> registers (A-in-regs),
// B streamed as [128 m][64 k] 16 KB chunks, 3-buffer, 1 barrier/step,
// counted vmcnt. XOR-swizzled LDS (inverse-swizzled global src).
// ---------------------------------------------------------------------------
__global__ __launch_bounds__(256, 1) void gemm_kernel(
        const __hip_bfloat16* __restrict__ h1b, const __hip_bfloat16* __restrict__ h2b,
        const float* __restrict__ sq1, const float* __restrict__ sq2,
        unsigned int* __restrict__ rowmin, unsigned int* __restrict__ colmin) {
    __shared__ __align__(16) unsigned short As[128 * 256];      // 64 KB
    __shared__ __align__(16) unsigned short Bs3[3][128 * 64];   // 48 KB
    __shared__ __align__(16) float sq2_lds[1024];               // 4 KB

    const int b    = blockIdx.x;       // batch (XCD = b%8 for all its tiles)
    const int tile = blockIdx.y;       // n-tile 0..7
    const int n0   = tile * 128;

    const int tid  = threadIdx.x;
    const int wave = tid >> 6;
    const int lane = tid & 63;
    const int wn   = (wave >> 1) * 64;
    const int wm   = (wave & 1) * 64;

    const char* Ag = (const char*)(h1b + ((size_t)b * NN + n0) * DD);
    const char* Bg = (const char*)(h2b + (size_t)b * MM * DD);

    const int krow = lane >> 4;   // 0..3
    const int rrow = lane & 15;   // 0..15
    const int lrow = krow * 4;
    const int lcol = rrow;

    // ---- prologue: s1 values for this lane's 16 rows (oldest loads) ----
    const float* s1 = sq1 + b * NN + n0;
    float s1v[16];
    #pragma unroll
    for (int i = 0; i < 4; ++i)
        #pragma unroll
        for (int r = 0; r < 4; ++r)
            s1v[i * 4 + r] = s1[wn + i * 16 + lrow + r];

    // ---- prologue staging ----
    // sq2 row -> LDS (4 KB linear)
    async_copy16((char*)sq2_lds + wave * 1024,
                 (const char*)(sq2 + b * MM) + wave * 1024 + lane * 16);

    // A panel 64 KB: 16 issues/thread, swizzled source
    {
        const int rsub = wave * 2 + (lane >> 5);            // r & 7
        const int cu   = (lane & 31) ^ rsub;                // src 16B unit
        #pragma unroll
        for (int c = 0; c < 16; ++c) {
            int r = c * 8 + rsub;
            async_copy16((char*)As + c * 4096 + wave * 1024,
                         Ag + (size_t)r * 512 + (cu << 4));
        }
    }

    // B chunk stager (16 KB: [128 m][64 k] of m-tile mt, k-step ks)
    const int rl  = lane >> 3;            // 0..7
    const int bcu = (lane & 7) ^ rl;      // src 16B unit within 128B k-slice
    #define STAGE_B(mt_, ks_, buf_)                                           \
        {                                                                     \
            char* ldsb = (char*)Bs3[buf_] + wave * 4096;                      \
            _Pragma("unroll")                                                 \
            for (int c = 0; c < 4; ++c) {                                     \
                int r_ = wave * 32 + c * 8 + rl;                              \
                async_copy16(ldsb + c * 1024,                                 \
                             Bg + (size_t)((mt_) * 128 + r_) * 512            \
                                + (size_t)(ks_) * 128 + (bcu << 4));          \
            }                                                                 \
        }

    STAGE_B(0, 0, 0);
    STAGE_B(0, 1, 1);

    // wait: all but newest 8 (B0,B1) done -> sq2 + A landed
    asm volatile("s_waitcnt vmcnt(8)" ::: "memory");
    __builtin_amdgcn_s_barrier();
    __builtin_amdgcn_sched_barrier(0);

    // ---- A panel -> registers: af[i][kq], kq = k-slice of 32 (8 total) ----
    short8 af[4][8];
    #pragma unroll
    for (int i = 0; i < 4; ++i) {
        #pragma unroll
        for (int kq = 0; kq < 8; ++kq) {
            int u = ((kq * 4 + krow) ^ (rrow & 7));
            af[i][kq] = *(const short8*)((const char*)As
                        + (size_t)(wn + i * 16 + rrow) * 512 + (u << 4));
        }
    }

    // ---- main loop: 8 m-tiles x 4 k-steps ----
    float rmin[4][4];
    #pragma unroll
    for (int i = 0; i < 4; ++i)
        #pragma unroll
        for (int r = 0; r < 4; ++r) rmin[i][r] = 3.0e38f;

    unsigned int* cm = colmin + b * MM;
    int bc = 0;   // buf of current step s (s % 3)

    #pragma unroll 1
    for (int mt = 0; mt < 8; ++mt) {
        floatx4 acc[4][4] = {};

        #pragma unroll
        for (int ks = 0; ks < 4; ++ks) {
            if (ks == 3) {
                if (mt == 7) { asm volatile("s_waitcnt vmcnt(0)" ::: "memory"); }
                else         { asm volatile("s_waitcnt vmcnt(4)" ::: "memory"); }
            } else {
                asm volatile("s_waitcnt vmcnt(4)" ::: "memory");
            }
            __builtin_amdgcn_s_barrier();
            __builtin_amdgcn_sched_barrier(0);

            // stage chunk s+2 into buf (s+2)%3
            {
                int mt2 = mt + ((ks + 2) >> 2);
                int ks2 = (ks + 2) & 3;
                int sb  = bc + 2; if (sb >= 3) sb -= 3;
                if (mt2 < 8) STAGE_B(mt2, ks2, sb);
            }

            // compute chunk s from buf bc
            const char* Bb = (const char*)Bs3[bc];
            #pragma unroll
            for (int kk = 0; kk < 2; ++kk) {
                short8 bfv[4];
                #pragma unroll
                for (int j = 0; j < 4; ++j) {
                    int u = ((kk * 4 + krow) ^ (rrow & 7));
                    bfv[j] = *(const short8*)(Bb
                             + (size_t)(wm + j * 16 + rrow) * 128 + (u << 4));
                }
                #pragma unroll
                for (int i = 0; i < 4; ++i)
                    #pragma unroll
                    for (int j = 0; j < 4; ++j)
                        acc[i][j] = __builtin_amdgcn_mfma_f32_16x16x32_bf16(
                            af[i][ks * 2 + kk], bfv[j], acc[i][j], 0, 0, 0);
            }
            bc = (bc == 2) ? 0 : bc + 1;
        }

        // ---- per-mt epilogue: dist + mins ----
        float s2v[4];
        #pragma unroll
        for (int j = 0; j < 4; ++j)
            s2v[j] = sq2_lds[mt * 128 + wm + j * 16 + lcol];

        float cmin[4] = {3.0e38f, 3.0e38f, 3.0e38f, 3.0e38f};
        #pragma unroll
        for (int i = 0; i < 4; ++i) {
            #pragma unroll
            for (int r = 0; r < 4; ++r) {
                float s1x = s1v[i * 4 + r];
                #pragma unroll
                for (int j = 0; j < 4; ++j) {
                    float dist = fmaxf(s1x + s2v[j] - 2.0f * acc[i][j][r], 0.0f);
                    rmin[i][r] = fminf(rmin[i][r], dist);
                    cmin[j]    = fminf(cmin[j], dist);
                }
            }
        }
        #pragma unroll
        for (int j = 0; j < 4; ++j) {
            float c = cmin[j];
            c = fminf(c, __shfl_xor(c, 16, 64));
            c = fminf(c, __shfl_xor(c, 32, 64));
            if (lane < 16)
                atomicMin(&cm[mt * 128 + wm + j * 16 + lcol], __float_as_uint(c));
        }
    }

    // ---- final rowmin ----
    unsigned int* rm = rowmin + b * NN + n0;
    #pragma unroll
    for (int i = 0; i < 4; ++i) {
        #pragma unroll
        for (int r = 0; r < 4; ++r) {
            float v = rmin[i][r];
            #pragma unroll
            for (int off = 1; off < 16; off <<= 1)
                v = fminf(v, __shfl_xor(v, off, 64));
            if (lcol == 0)
                atomicMin(&rm[wn + i * 16 + lrow + r], __float_as_uint(v));
        }
    }
    #undef STAGE_B
}

// ---------------------------------------------------------------------------
__global__ __launch_bounds__(256) void finalize_kernel(
        const unsigned int* __restrict__ rowmin,
        const unsigned int* __restrict__ colmin,
        float* __restrict__ out) {
    int b = blockIdx.x;
    int tid = threadIdx.x;
    float s = 0.0f;
    for (int i = tid; i < NN; i += 256) s += __uint_as_float(rowmin[b * NN + i]);
    for (int i = tid; i < MM; i += 256) s += __uint_as_float(colmin[b * MM + i]);
    #pragma unroll
    for (int off = 32; off; off >>= 1) s += __shfl_xor(s, off, 64);
    __shared__ float wsum[4];
    if ((tid & 63) == 0) wsum[tid >> 6] = s;
    __syncthreads();
    if (tid == 0) out[b] = (wsum[0] + wsum[1] + wsum[2] + wsum[3]) * (1.0f / 1024.0f);
}

// ---------------------------------------------------------------------------
extern "C" void kernel_launch(void* const* d_in, const int* in_sizes, int n_in,
                              void* d_out, int out_size, void* d_ws, size_t ws_size,
                              hipStream_t stream) {
    const float* h1 = (const float*)d_in[0];
    const float* h2 = (const float*)d_in[1];
    float* out = (float*)d_out;

    char* ws = (char*)d_ws;
    const size_t bf_bytes = (size_t)BB * NN * DD * sizeof(unsigned short); // 16 MB
    __hip_bfloat16* h1b = (__hip_bfloat16*)ws;
    __hip_bfloat16* h2b = (__hip_bfloat16*)(ws + bf_bytes);
    float* sq1 = (float*)(ws + 2 * bf_bytes);
    float* sq2 = sq1 + BB * NN;
    unsigned int* rowmin = (unsigned int*)(sq2 + BB * MM);
    unsigned int* colmin = rowmin + BB * NN;

    hipLaunchKernelGGL(init_minbuf, dim3(256), dim3(256), 0, stream, rowmin);

    hipLaunchKernelGGL(convert_kernel, dim3((BB * NN + BB * MM) / 4), dim3(256), 0, stream,
                       h1, h2, h1b, h2b, sq1, sq2);

    hipLaunchKernelGGL(gemm_kernel, dim3(BB, 8), dim3(256), 0, stream,
                       h1b, h2b, sq1, sq2, rowmin, colmin);

    hipLaunchKernelGGL(finalize_kernel, dim3(BB), dim3(256), 0, stream,
                       rowmin, colmin, out);
}

// Round 4
// 61.023 us; speedup vs baseline: 1.4148x; 1.0897x over previous
//
#include <hip/hip_runtime.h>
#include <hip/hip_bf16.h>
#include <stdint.h>

#define BB 32
#define NN 1024
#define MM 1024
#define DD 256

typedef __attribute__((ext_vector_type(8))) short short8;
typedef __attribute__((ext_vector_type(4))) float floatx4;

__device__ inline unsigned short f2bf(float x) {
    union { __hip_bfloat16 h; unsigned short u; } cv;
    cv.h = __float2bfloat16(x);
    return cv.u;
}

// async global->LDS. LDS dest = wave-uniform base; HW adds lane*size.
__device__ inline void async_copy16(void* lds, const void* g) {
    __builtin_amdgcn_global_load_lds(
        (const __attribute__((address_space(1))) unsigned int*)g,
        (__attribute__((address_space(3))) unsigned int*)lds, 16, 0, 0);
}
__device__ inline void async_copy4(void* lds, const void* g) {
    __builtin_amdgcn_global_load_lds(
        (const __attribute__((address_space(1))) unsigned int*)g,
        (__attribute__((address_space(3))) unsigned int*)lds, 4, 0, 0);
}

// ---------------------------------------------------------------------------
__global__ __launch_bounds__(256) void init_minbuf(unsigned int* __restrict__ p) {
    p[blockIdx.x * 256 + threadIdx.x] = 0x7F800000u; // +inf
}

// ---------------------------------------------------------------------------
// Convert fp32 -> bf16 + per-row sum of squares (fp32 exact). One wave/row.
// ---------------------------------------------------------------------------
__global__ __launch_bounds__(256) void convert_kernel(
        const float* __restrict__ h1, const float* __restrict__ h2,
        __hip_bfloat16* __restrict__ h1b, __hip_bfloat16* __restrict__ h2b,
        float* __restrict__ sq1, float* __restrict__ sq2) {
    int wave = blockIdx.x * 4 + (threadIdx.x >> 6);
    int lane = threadIdx.x & 63;
    const int total1 = BB * NN;

    const float* src;
    __hip_bfloat16* dst;
    float* sq;
    int row;
    if (wave < total1) { src = h1; dst = h1b; sq = sq1; row = wave; }
    else               { src = h2; dst = h2b; sq = sq2; row = wave - total1; }

    const float4* p = (const float4*)(src + (size_t)row * DD);
    float4 v = p[lane];

    float s = v.x * v.x + v.y * v.y + v.z * v.z + v.w * v.w;
    #pragma unroll
    for (int off = 32; off; off >>= 1) s += __shfl_xor(s, off, 64);

    ushort4 o;
    o.x = f2bf(v.x); o.y = f2bf(v.y); o.z = f2bf(v.z); o.w = f2bf(v.w);
    *(ushort4*)((unsigned short*)(dst + (size_t)row * DD) + lane * 4) = o;

    if (lane == 0) sq[row] = s;
}

// ---------------------------------------------------------------------------
// A-resident batched GEMM + fused Hausdorff epilogue. 512 threads = 8 waves
// (2 waves/SIMD for latency hiding), 1 block/CU (116 KB LDS).
// Wave layout 2n x 4m: each wave = 64n x 32m, A panel in registers.
// B streamed [128 m][64 k] 16 KB chunks, 3-buffer, counted vmcnt(2).
// ---------------------------------------------------------------------------
__global__ __launch_bounds__(512, 2) void gemm_kernel(
        const __hip_bfloat16* __restrict__ h1b, const __hip_bfloat16* __restrict__ h2b,
        const float* __restrict__ sq1, const float* __restrict__ sq2,
        unsigned int* __restrict__ rowmin, unsigned int* __restrict__ colmin) {
    __shared__ __align__(16) unsigned short As[128 * 256];      // 64 KB
    __shared__ __align__(16) unsigned short Bs3[3][128 * 64];   // 48 KB
    __shared__ __align__(16) float sq2_lds[1024];               // 4 KB

    const int b    = blockIdx.x;       // batch; XCD = (b + 32*tile)%8 = b%8
    const int tile = blockIdx.y;       // n-tile 0..7
    const int n0   = tile * 128;

    const int tid  = threadIdx.x;
    const int wave = tid >> 6;         // 0..7
    const int lane = tid & 63;
    const int wn   = (wave >> 2) * 64;       // {0,64}
    const int wm   = (wave & 3) * 32;        // {0,32,64,96}

    const char* Ag = (const char*)(h1b + ((size_t)b * NN + n0) * DD);
    const char* Bg = (const char*)(h2b + (size_t)b * MM * DD);

    const int krow = lane >> 4;   // 0..3
    const int rrow = lane & 15;   // 0..15
    const int rx   = rrow & 7;
    const int lrow = krow * 4;
    const int lcol = rrow;

    // ---- prologue vmem issues (in order; counted against vmcnt) ----
    // 1) s1 norms for this lane's 16 rows: 4 x float4
    const float4* s1p = (const float4*)(sq1 + b * NN + n0 + wn + lrow);
    float4 s1v4[4];
    #pragma unroll
    for (int i = 0; i < 4; ++i) s1v4[i] = s1p[i * 4];

    // 2) sq2 -> LDS (4 KB linear, size-4 copies, 2 issues/thread)
    #pragma unroll
    for (int t = 0; t < 2; ++t)
        async_copy4((char*)sq2_lds + t * 2048 + wave * 256,
                    (const char*)(sq2 + b * MM) + t * 2048 + wave * 256 + lane * 4);

    // 3) A panel 64 KB: 64 chunks of 1 KB (2 rows each), 8 issues/thread.
    //    LDS linear; global src col inverse-XOR-swizzled.
    #pragma unroll
    for (int t = 0; t < 8; ++t) {
        int ch = t * 8 + wave;
        int r  = ch * 2 + (lane >> 5);
        int cu = (lane & 31) ^ (r & 7);
        async_copy16((char*)As + ch * 1024, Ag + (size_t)r * 512 + (cu << 4));
    }

    // 4) B chunk stager: 16 KB = 16 chunks of 1 KB (8 rows), 2 issues/thread
    const int rl  = lane >> 3;            // 0..7 (row within chunk)
    const int bcu = (lane & 7) ^ rl;      // inverse-swizzled src 16B unit
    #define STAGE_B(mt_, ks_, buf_)                                           \
        {                                                                     \
            _Pragma("unroll")                                                 \
            for (int c = 0; c < 2; ++c) {                                     \
                int ch_ = wave * 2 + c;                                       \
                int r_  = ch_ * 8 + rl;                                       \
                async_copy16((char*)Bs3[buf_] + ch_ * 1024,                   \
                             Bg + (size_t)((mt_) * 128 + r_) * 512            \
                                + (size_t)(ks_) * 128 + (bcu << 4));          \
            }                                                                 \
        }

    STAGE_B(0, 0, 0);
    STAGE_B(0, 1, 1);

    // A + sq2 + s1v done; B0(2)+B1(2) may remain in flight
    asm volatile("s_waitcnt vmcnt(4)" ::: "memory");
    __builtin_amdgcn_s_barrier();
    __builtin_amdgcn_sched_barrier(0);

    // ---- A panel -> registers: af[i][kq] (kq = K-slice of 32) ----
    short8 af[4][8];
    #pragma unroll
    for (int i = 0; i < 4; ++i) {
        #pragma unroll
        for (int kq = 0; kq < 8; ++kq) {
            int u = (kq * 4 + krow) ^ rx;
            af[i][kq] = *(const short8*)((const char*)As
                        + (size_t)(wn + i * 16 + rrow) * 512 + (u << 4));
        }
    }

    float rmin[4][4];
    #pragma unroll
    for (int i = 0; i < 4; ++i)
        #pragma unroll
        for (int r = 0; r < 4; ++r) rmin[i][r] = 3.0e38f;

    unsigned int* cm = colmin + b * MM;
    int bc = 0;

    #pragma unroll 1
    for (int mt = 0; mt < 8; ++mt) {
        floatx4 acc[4][2] = {};

        #pragma unroll
        for (int ks = 0; ks < 4; ++ks) {
            if (mt == 7 && ks == 3) { asm volatile("s_waitcnt vmcnt(0)" ::: "memory"); }
            else                    { asm volatile("s_waitcnt vmcnt(2)" ::: "memory"); }
            __builtin_amdgcn_s_barrier();
            __builtin_amdgcn_sched_barrier(0);

            // stage chunk s+2
            {
                int s2 = mt * 4 + ks + 2;
                if (s2 < 32) {
                    int mt2 = s2 >> 2, ks2 = s2 & 3;
                    int sb = bc + 2; if (sb >= 3) sb -= 3;
                    STAGE_B(mt2, ks2, sb);
                }
            }

            // compute chunk s from buf bc
            const char* Bb = (const char*)Bs3[bc];
            #pragma unroll
            for (int kk = 0; kk < 2; ++kk) {
                short8 bfv[2];
                #pragma unroll
                for (int j = 0; j < 2; ++j) {
                    int u = (kk * 4 + krow) ^ rx;
                    bfv[j] = *(const short8*)(Bb
                             + (size_t)(wm + j * 16 + rrow) * 128 + (u << 4));
                }
                #pragma unroll
                for (int i = 0; i < 4; ++i)
                    #pragma unroll
                    for (int j = 0; j < 2; ++j)
                        acc[i][j] = __builtin_amdgcn_mfma_f32_16x16x32_bf16(
                            af[i][ks * 2 + kk], bfv[j], acc[i][j], 0, 0, 0);
            }
            bc = (bc == 2) ? 0 : bc + 1;
        }

        // ---- per-mt epilogue: dist + mins ----
        float s2v[2];
        #pragma unroll
        for (int j = 0; j < 2; ++j)
            s2v[j] = sq2_lds[mt * 128 + wm + j * 16 + lcol];

        float cmin[2] = {3.0e38f, 3.0e38f};
        #pragma unroll
        for (int i = 0; i < 4; ++i) {
            #pragma unroll
            for (int r = 0; r < 4; ++r) {
                float s1x = ((const float*)&s1v4[i])[r];
                #pragma unroll
                for (int j = 0; j < 2; ++j) {
                    float dist = fmaxf(s1x + s2v[j] - 2.0f * acc[i][j][r], 0.0f);
                    rmin[i][r] = fminf(rmin[i][r], dist);
                    cmin[j]    = fminf(cmin[j], dist);
                }
            }
        }
        #pragma unroll
        for (int j = 0; j < 2; ++j) {
            float c = cmin[j];
            c = fminf(c, __shfl_xor(c, 16, 64));
            c = fminf(c, __shfl_xor(c, 32, 64));
            if (lane < 16)
                atomicMin(&cm[mt * 128 + wm + j * 16 + lcol], __float_as_uint(c));
        }
    }

    // ---- final rowmin ----
    unsigned int* rm = rowmin + b * NN + n0;
    #pragma unroll
    for (int i = 0; i < 4; ++i) {
        #pragma unroll
        for (int r = 0; r < 4; ++r) {
            float v = rmin[i][r];
            #pragma unroll
            for (int off = 1; off < 16; off <<= 1)
                v = fminf(v, __shfl_xor(v, off, 64));
            if (lcol == 0)
                atomicMin(&rm[wn + i * 16 + lrow + r], __float_as_uint(v));
        }
    }
    #undef STAGE_B
}

// ---------------------------------------------------------------------------
__global__ __launch_bounds__(256) void finalize_kernel(
        const unsigned int* __restrict__ rowmin,
        const unsigned int* __restrict__ colmin,
        float* __restrict__ out) {
    int b = blockIdx.x;
    int tid = threadIdx.x;
    float s = 0.0f;
    for (int i = tid; i < NN; i += 256) s += __uint_as_float(rowmin[b * NN + i]);
    for (int i = tid; i < MM; i += 256) s += __uint_as_float(colmin[b * MM + i]);
    #pragma unroll
    for (int off = 32; off; off >>= 1) s += __shfl_xor(s, off, 64);
    __shared__ float wsum[4];
    if ((tid & 63) == 0) wsum[tid >> 6] = s;
    __syncthreads();
    if (tid == 0) out[b] = (wsum[0] + wsum[1] + wsum[2] + wsum[3]) * (1.0f / 1024.0f);
}

// ---------------------------------------------------------------------------
extern "C" void kernel_launch(void* const* d_in, const int* in_sizes, int n_in,
                              void* d_out, int out_size, void* d_ws, size_t ws_size,
                              hipStream_t stream) {
    const float* h1 = (const float*)d_in[0];
    const float* h2 = (const float*)d_in[1];
    float* out = (float*)d_out;

    char* ws = (char*)d_ws;
    const size_t bf_bytes = (size_t)BB * NN * DD * sizeof(unsigned short); // 16 MB
    __hip_bfloat16* h1b = (__hip_bfloat16*)ws;
    __hip_bfloat16* h2b = (__hip_bfloat16*)(ws + bf_bytes);
    float* sq1 = (float*)(ws + 2 * bf_bytes);
    float* sq2 = sq1 + BB * NN;
    unsigned int* rowmin = (unsigned int*)(sq2 + BB * MM);
    unsigned int* colmin = rowmin + BB * NN;

    hipLaunchKernelGGL(init_minbuf, dim3(256), dim3(256), 0, stream, rowmin);

    hipLaunchKernelGGL(convert_kernel, dim3((BB * NN + BB * MM) / 4), dim3(256), 0, stream,
                       h1, h2, h1b, h2b, sq1, sq2);

    hipLaunchKernelGGL(gemm_kernel, dim3(BB, 8), dim3(512), 0, stream,
                       h1b, h2b, sq1, sq2, rowmin, colmin);

    hipLaunchKernelGGL(finalize_kernel, dim3(BB), dim3(256), 0, stream,
                       rowmin, colmin, out);
}